// Round 4
// baseline (1049.447 us; speedup 1.0000x reference)
//
#include <hip/hip_runtime.h>

typedef _Float16 half8_t __attribute__((ext_vector_type(8)));
typedef _Float16 half4_t __attribute__((ext_vector_type(4)));
typedef float    f32x4   __attribute__((ext_vector_type(4)));

#define LSEQ    2048
#define DIM     64
#define ROWS    16
#define TOPK    64
#define CAP     128
#define NROWTOT 65536   // B*H*L = 2*16*2048

// ---------------- fp32 -> fp16 conversion prepass ----------------
__global__ void cvt_f16_kernel(const float* __restrict__ Q, const float* __restrict__ K,
                               _Float16* __restrict__ Q16, _Float16* __restrict__ K16, int n4)
{
    int i = blockIdx.x * blockDim.x + threadIdx.x;
    if (i >= n4) return;
    float4 q = reinterpret_cast<const float4*>(Q)[i];
    float4 k = reinterpret_cast<const float4*>(K)[i];
    half4_t hq = { (_Float16)q.x, (_Float16)q.y, (_Float16)q.z, (_Float16)q.w };
    half4_t hk = { (_Float16)k.x, (_Float16)k.y, (_Float16)k.z, (_Float16)k.w };
    reinterpret_cast<half4_t*>(Q16)[i] = hq;
    reinterpret_cast<half4_t*>(K16)[i] = hk;
}

// ---------------- main: scores (f16 MFMA) + exact top-k + PV ----------------
template <bool PRE>
__global__ __launch_bounds__(512, 4) void topk_attn_kernel(
    const float* __restrict__ Qf, const float* __restrict__ Kf, const float* __restrict__ Vf,
    const _Float16* __restrict__ Q16, const _Float16* __restrict__ K16,
    float* __restrict__ Out)
{
    __shared__ _Float16 sc[ROWS][LSEQ];     // 64 KB fp16 scores
    __shared__ float    qlds[ROWS][DIM];    // 4 KB exact Q
    __shared__ int      candIdx[8][CAP];
    __shared__ int      pvK[8][TOPK];
    __shared__ float    pvW[8][TOPK];

    const int tid  = threadIdx.x;
    const int wave = tid >> 6;
    const int lane = tid & 63;

    const long rowbase  = (long)blockIdx.x * ROWS;       // global query-row base
    const long headbase = (rowbase >> 11) << 11;         // first row of this (b,h) head

    // stage exact fp32 Q rows for candidate recompute
    for (int i = tid; i < ROWS * DIM; i += 512)
        qlds[i >> 6][i & 63] = Qf[rowbase * DIM + i];

    // ---- Phase 1: fp16 scores via MFMA, direct global->fragment loads ----
    const int g = lane >> 4;     // k-chunk selector
    const int r = lane & 15;     // row (A) / col (B) within 16x16 tile

    half8_t a0, a1;
    if constexpr (PRE) {
        a0 = *reinterpret_cast<const half8_t*>(Q16 + (rowbase + r) * DIM + g * 8);
        a1 = *reinterpret_cast<const half8_t*>(Q16 + (rowbase + r) * DIM + 32 + g * 8);
    } else {
        const float* qp = Qf + (rowbase + r) * DIM + g * 8;
        #pragma unroll
        for (int j = 0; j < 8; ++j) { a0[j] = (_Float16)qp[j]; a1[j] = (_Float16)qp[32 + j]; }
    }

    #pragma unroll 4
    for (int t = 0; t < 16; ++t) {
        const int key = t * 128 + wave * 16 + r;
        half8_t b0, b1;
        if constexpr (PRE) {
            const _Float16* kp = K16 + (headbase + key) * DIM + g * 8;
            b0 = *reinterpret_cast<const half8_t*>(kp);
            b1 = *reinterpret_cast<const half8_t*>(kp + 32);
        } else {
            const float* kp = Kf + (headbase + key) * DIM + g * 8;
            #pragma unroll
            for (int j = 0; j < 8; ++j) { b0[j] = (_Float16)kp[j]; b1[j] = (_Float16)kp[32 + j]; }
        }
        f32x4 acc = {0.f, 0.f, 0.f, 0.f};
        acc = __builtin_amdgcn_mfma_f32_16x16x32_f16(a0, b0, acc, 0, 0, 0);
        acc = __builtin_amdgcn_mfma_f32_16x16x32_f16(a1, b1, acc, 0, 0, 0);
        #pragma unroll
        for (int j = 0; j < 4; ++j)
            sc[g * 4 + j][key] = (_Float16)acc[j];   // C: col=lane&15, row=(lane>>4)*4+j
    }
    __syncthreads();

    // ---- Phase 2: per-wave exact top-64 + softmax + PV (2 rows/wave) ----
    const unsigned long long mlt = (1ull << lane) - 1ull;
    const int perm = lane & 3;   // XOR chunk stagger -> conflict-free ds_read_b128

    for (int rr = 0; rr < 2; ++rr) {
        const int row = wave * 2 + rr;

        // 32 fp16 scores per lane, kept PACKED (16 VGPRs, no fp32 expansion)
        const half8_t* sp = reinterpret_cast<const half8_t*>(&sc[row][lane * 32]);
        half8_t h[4];
        h[0] = sp[0 ^ perm];
        h[1] = sp[1 ^ perm];
        h[2] = sp[2 ^ perm];
        h[3] = sp[3 ^ perm];

        // row statistics (convert on the fly; no arrays)
        float sm = 0.f, s2 = 0.f;
        #pragma unroll
        for (int i = 0; i < 4; ++i)
            #pragma unroll
            for (int e = 0; e < 8; ++e) {
                const float x = (float)h[i][e];
                sm += x;
                s2 = fmaf(x, x, s2);
            }
        #pragma unroll
        for (int o = 32; o > 0; o >>= 1) {
            sm += __shfl_xor(sm, o);
            s2 += __shfl_xor(s2, o);
        }
        const float mu  = sm * (1.f / LSEQ);
        const float sig = sqrtf(fmaxf(s2 * (1.f / LSEQ) - mu * mu, 0.f));

        // adaptive threshold in fp16 domain: count(> T0+E2) >= 64 (containment),
        // count(>= T0) <= CAP (capacity).  Ballot counting: v_cmp_f16 + s_bcnt.
        const float E2 = 0.30f;   // 2 * conservative fp16-score error bound
        float T0  = mu + 1.60f * sig;
        float stp = 0.5f * sig + 0.05f;
        for (int it = 0; it < 16; ++it) {
            const _Float16 hT  = (_Float16)T0;
            const _Float16 hT2 = (_Float16)(T0 + E2);
            int ca = 0, ch = 0;
            #pragma unroll
            for (int i = 0; i < 4; ++i)
                #pragma unroll
                for (int e = 0; e < 8; ++e) {
                    ca += __popcll(__ballot(h[i][e] >= hT));
                    ch += __popcll(__ballot(h[i][e] >  hT2));
                }
            if (ch >= TOPK && ca <= CAP) break;
            T0 += (ca > CAP) ? stp : -stp;
            stp *= 0.6f;
        }

        // compact candidate key indices into LDS (ballot-scan per element step)
        const _Float16 hTf = (_Float16)T0;
        int total = 0;
        #pragma unroll
        for (int i = 0; i < 4; ++i)
            #pragma unroll
            for (int e = 0; e < 8; ++e) {
                const bool c = (h[i][e] >= hTf);
                const unsigned long long b = __ballot(c);
                const int pos = total + __popcll(b & mlt);
                if (c && pos < CAP)
                    candIdx[wave][pos] = lane * 32 + ((i ^ perm) << 3) + e;
                total += __popcll(b);
            }
        int nAll = (total > CAP) ? CAP : total;
        asm volatile("s_waitcnt lgkmcnt(0)" ::: "memory");

        // exact fp32 recompute of candidate scores (<=2 per lane)
        float ex[2]; unsigned us[2]; int ci[2];
        #pragma unroll
        for (int p = 0; p < 2; ++p) {
            const int c = lane + 64 * p;
            const bool valid = (c < nAll);
            const int key = valid ? candIdx[wave][c] : 0;
            ci[p] = key;
            float dot = 0.f;
            const float4* kp4 = reinterpret_cast<const float4*>(Kf + (headbase + key) * DIM);
            #pragma unroll
            for (int chk = 0; chk < 16; ++chk) {
                const float4 kk = kp4[chk];
                dot = fmaf(kk.x, qlds[row][chk * 4 + 0], dot);
                dot = fmaf(kk.y, qlds[row][chk * 4 + 1], dot);
                dot = fmaf(kk.z, qlds[row][chk * 4 + 2], dot);
                dot = fmaf(kk.w, qlds[row][chk * 4 + 3], dot);
            }
            ex[p] = dot;
            unsigned u = __float_as_uint(dot);
            u ^= (unsigned)((int)u >> 31) | 0x80000000u;   // order-preserving transform
            us[p] = valid ? u : 0u;
        }

        // exact 64th-largest via 32-step bitwise ballot descent
        unsigned cut = 0u;
        #pragma unroll
        for (int b = 31; b >= 0; --b) {
            const unsigned trial = cut | (1u << b);
            const int cnt = __popcll(__ballot(us[0] >= trial)) +
                            __popcll(__ballot(us[1] >= trial));
            if (cnt >= TOPK) cut = trial;
        }

        // selection (ties on exact fp32 scores are measure-zero on this data)
        const unsigned long long beq0 = __ballot(us[0] == cut);
        const unsigned long long beq1 = __ballot(us[1] == cut);
        const int cntGt = __popcll(__ballot(us[0] > cut)) + __popcll(__ballot(us[1] > cut));
        const int need  = TOPK - cntGt;
        const int rank0 = __popcll(beq0 & mlt);
        const int rank1 = __popcll(beq0) + __popcll(beq1 & mlt);
        const bool sel0 = (us[0] > cut) || ((us[0] == cut) && (rank0 < need));
        const bool sel1 = (us[1] > cut) || ((us[1] == cut) && (rank1 < need));

        // softmax over selected (exact fp32)
        float mxe = fmaxf(sel0 ? ex[0] : -1e30f, sel1 ? ex[1] : -1e30f);
        #pragma unroll
        for (int o = 32; o > 0; o >>= 1) mxe = fmaxf(mxe, __shfl_xor(mxe, o));
        const float w0 = sel0 ? expf(ex[0] - mxe) : 0.f;
        const float w1 = sel1 ? expf(ex[1] - mxe) : 0.f;
        float zs = w0 + w1;
        #pragma unroll
        for (int o = 32; o > 0; o >>= 1) zs += __shfl_xor(zs, o);
        const float inv = 1.f / zs;

        // compact selected (key, weight) pairs
        pvK[wave][lane] = 0;          // defensive init (poisoned LDS)
        pvW[wave][lane] = 0.f;
        const unsigned long long bs0 = __ballot(sel0);
        const unsigned long long bs1 = __ballot(sel1);
        const int pos0 = __popcll(bs0 & mlt);
        const int pos1 = __popcll(bs0) + __popcll(bs1 & mlt);
        if (sel0) { pvK[wave][pos0] = ci[0]; pvW[wave][pos0] = w0 * inv; }
        if (sel1) { pvK[wave][pos1] = ci[1]; pvW[wave][pos1] = w1 * inv; }
        asm volatile("s_waitcnt lgkmcnt(0)" ::: "memory");

        // PV: lane = d, gather 64 V rows (coalesced 256B per row)
        float acc = 0.f;
        #pragma unroll 16
        for (int i = 0; i < TOPK; ++i) {
            const int   ki = pvK[wave][i];
            const float wi = pvW[wave][i];
            acc = fmaf(wi, Vf[(headbase + ki) * DIM + lane], acc);
        }
        Out[(rowbase + row) * DIM + lane] = acc;
    }
}

extern "C" void kernel_launch(void* const* d_in, const int* in_sizes, int n_in,
                              void* d_out, int out_size, void* d_ws, size_t ws_size,
                              hipStream_t stream)
{
    const float* Q = (const float*)d_in[0];
    const float* K = (const float*)d_in[1];
    const float* V = (const float*)d_in[2];
    float* Out = (float*)d_out;

    const int nElem = 2 * 16 * 2048 * 64;   // 4194304 per tensor
    const size_t needWs = (size_t)2 * (size_t)nElem * sizeof(_Float16);

    if (ws_size >= needWs) {
        _Float16* Q16 = (_Float16*)d_ws;
        _Float16* K16 = Q16 + nElem;
        cvt_f16_kernel<<<(nElem / 4) / 256, 256, 0, stream>>>(Q, K, Q16, K16, nElem / 4);
        topk_attn_kernel<true><<<NROWTOT / ROWS, 512, 0, stream>>>(Q, K, V, Q16, K16, Out);
    } else {
        topk_attn_kernel<false><<<NROWTOT / ROWS, 512, 0, stream>>>(Q, K, V, nullptr, nullptr, Out);
    }
}

// Round 5
// 802.166 us; speedup vs baseline: 1.3083x; 1.3083x over previous
//
#include <hip/hip_runtime.h>

typedef _Float16 half8_t __attribute__((ext_vector_type(8)));
typedef _Float16 half4_t __attribute__((ext_vector_type(4)));
typedef float    f32x4   __attribute__((ext_vector_type(4)));

#define LSEQ    2048
#define DIM     64
#define ROWS    16
#define TOPK    64
#define CAP     128
#define NROWTOT 65536   // B*H*L = 2*16*2048
#define SCSTR   (LSEQ + 8)   // +8 halfs pad: row stride 4112 B kills write bank conflicts

static __device__ __forceinline__ _Float16 u16_as_h(unsigned short u) {
    union { unsigned short u; _Float16 h; } c; c.u = u; return c.h;
}

// ---------------- fp32 -> fp16 conversion prepass ----------------
__global__ void cvt_f16_kernel(const float* __restrict__ Q, const float* __restrict__ K,
                               _Float16* __restrict__ Q16, _Float16* __restrict__ K16, int n4)
{
    int i = blockIdx.x * blockDim.x + threadIdx.x;
    if (i >= n4) return;
    float4 q = reinterpret_cast<const float4*>(Q)[i];
    float4 k = reinterpret_cast<const float4*>(K)[i];
    half4_t hq = { (_Float16)q.x, (_Float16)q.y, (_Float16)q.z, (_Float16)q.w };
    half4_t hk = { (_Float16)k.x, (_Float16)k.y, (_Float16)k.z, (_Float16)k.w };
    reinterpret_cast<half4_t*>(Q16)[i] = hq;
    reinterpret_cast<half4_t*>(K16)[i] = hk;
}

// ---------------- main: scores (f16 MFMA) + exact top-k + PV ----------------
// waves_per_eu(4,4): LDS already limits us to 2 blocks/CU = 4 waves/EU, so a
// 128-VGPR budget is free; without the max bound the compiler squeezed to 64
// VGPRs and spilled ~256 B/thread (534 MB of scratch writes, round 4).
template <bool PRE>
__global__ __launch_bounds__(512) __attribute__((amdgpu_waves_per_eu(4, 4)))
void topk_attn_kernel(
    const float* __restrict__ Qf, const float* __restrict__ Kf, const float* __restrict__ Vf,
    const _Float16* __restrict__ Q16, const _Float16* __restrict__ K16,
    float* __restrict__ Out)
{
    __shared__ _Float16 sc[ROWS][SCSTR];    // ~64 KB fp16 scores (padded rows)
    __shared__ float    qlds[ROWS][DIM];    // 4 KB exact Q
    __shared__ int      candIdx[8][CAP];
    __shared__ int      pvK[8][TOPK];
    __shared__ float    pvW[8][TOPK];

    const int tid  = threadIdx.x;
    const int wave = tid >> 6;
    const int lane = tid & 63;

    const long rowbase  = (long)blockIdx.x * ROWS;       // global query-row base
    const long headbase = (rowbase >> 11) << 11;         // first row of this (b,h) head

    // stage exact fp32 Q rows for candidate recompute
    for (int i = tid; i < ROWS * DIM; i += 512)
        qlds[i >> 6][i & 63] = Qf[rowbase * DIM + i];

    // ---- Phase 1: fp16 scores via MFMA, direct global->fragment loads ----
    const int g = lane >> 4;     // k-chunk selector
    const int r = lane & 15;     // row (A) / col (B) within 16x16 tile

    half8_t a0, a1;
    if constexpr (PRE) {
        a0 = *reinterpret_cast<const half8_t*>(Q16 + (rowbase + r) * DIM + g * 8);
        a1 = *reinterpret_cast<const half8_t*>(Q16 + (rowbase + r) * DIM + 32 + g * 8);
    } else {
        const float* qp = Qf + (rowbase + r) * DIM + g * 8;
        #pragma unroll
        for (int j = 0; j < 8; ++j) { a0[j] = (_Float16)qp[j]; a1[j] = (_Float16)qp[32 + j]; }
    }

    #pragma unroll 4
    for (int t = 0; t < 16; ++t) {
        const int key = t * 128 + wave * 16 + r;
        half8_t b0, b1;
        if constexpr (PRE) {
            const _Float16* kp = K16 + (headbase + key) * DIM + g * 8;
            b0 = *reinterpret_cast<const half8_t*>(kp);
            b1 = *reinterpret_cast<const half8_t*>(kp + 32);
        } else {
            const float* kp = Kf + (headbase + key) * DIM + g * 8;
            #pragma unroll
            for (int j = 0; j < 8; ++j) { b0[j] = (_Float16)kp[j]; b1[j] = (_Float16)kp[32 + j]; }
        }
        f32x4 acc = {0.f, 0.f, 0.f, 0.f};
        acc = __builtin_amdgcn_mfma_f32_16x16x32_f16(a0, b0, acc, 0, 0, 0);
        acc = __builtin_amdgcn_mfma_f32_16x16x32_f16(a1, b1, acc, 0, 0, 0);
        #pragma unroll
        for (int j = 0; j < 4; ++j)
            sc[g * 4 + j][key] = (_Float16)acc[j];   // C: col=lane&15, row=(lane>>4)*4+j
    }
    __syncthreads();

    // ---- Phase 2: per-wave exact top-64 + softmax + PV (2 rows/wave) ----
    const unsigned long long mlt = (1ull << lane) - 1ull;
    const int perm = lane & 3;   // XOR chunk stagger -> uniform-bank ds_read_b128

    for (int rr = 0; rr < 2; ++rr) {
        const int row = wave * 2 + rr;

        // 32 fp16 scores per lane, kept PACKED (16 VGPRs, no fp32 expansion)
        const half8_t* sp = reinterpret_cast<const half8_t*>(&sc[row][lane * 32]);
        half8_t h[4];
        h[0] = sp[0 ^ perm];
        h[1] = sp[1 ^ perm];
        h[2] = sp[2 ^ perm];
        h[3] = sp[3 ^ perm];

        // exact 64th-largest fp16 score via 16-step bitwise descent over
        // sortable-u16 codes (count by v_cmp_f16 ballots; wave-uniform SALU).
        unsigned cut16 = 0u;
        for (int b = 15; b >= 0; --b) {
            const unsigned trial = cut16 | (1u << b);
            const unsigned short tb = (trial & 0x8000u)
                                        ? (unsigned short)(trial ^ 0x8000u)
                                        : (unsigned short)(~trial);
            const _Float16 T = u16_as_h(tb);
            int cnt = 0;
            #pragma unroll
            for (int i = 0; i < 4; ++i)
                #pragma unroll
                for (int e = 0; e < 8; ++e)
                    cnt += __popcll(__ballot(h[i][e] >= T));
            if (cnt >= TOPK) cut16 = trial;
        }
        const unsigned short cb = (cut16 & 0x8000u)
                                    ? (unsigned short)(cut16 ^ 0x8000u)
                                    : (unsigned short)(~cut16);
        const float H64 = (float)u16_as_h(cb);
        // candidate set: h >= H64 - margin.  margin 0.35 >> 2*max fp16-score
        // error (~0.12 for D=64, |s|<~40) -> provable containment of exact top-64.
        const _Float16 hTf = (_Float16)(H64 - 0.35f);

        // compact candidate key indices into LDS (ballot-scan per element step)
        int total = 0;
        #pragma unroll
        for (int i = 0; i < 4; ++i)
            #pragma unroll
            for (int e = 0; e < 8; ++e) {
                const bool c = (h[i][e] >= hTf);
                const unsigned long long b = __ballot(c);
                const int pos = total + __popcll(b & mlt);
                if (c && pos < CAP)
                    candIdx[wave][pos] = lane * 32 + ((i ^ perm) << 3) + e;
                total += __popcll(b);
            }
        int nAll = (total > CAP) ? CAP : total;
        asm volatile("s_waitcnt lgkmcnt(0)" ::: "memory");

        // exact fp32 recompute of candidate scores (<=2 per lane)
        float ex[2]; unsigned us[2]; int ci[2];
        #pragma unroll
        for (int p = 0; p < 2; ++p) {
            const int c = lane + 64 * p;
            const bool valid = (c < nAll);
            const int key = valid ? candIdx[wave][c] : 0;
            ci[p] = key;
            float dot = 0.f;
            const float4* kp4 = reinterpret_cast<const float4*>(Kf + (headbase + key) * DIM);
            #pragma unroll
            for (int chk = 0; chk < 16; ++chk) {
                const float4 kk = kp4[chk];
                dot = fmaf(kk.x, qlds[row][chk * 4 + 0], dot);
                dot = fmaf(kk.y, qlds[row][chk * 4 + 1], dot);
                dot = fmaf(kk.z, qlds[row][chk * 4 + 2], dot);
                dot = fmaf(kk.w, qlds[row][chk * 4 + 3], dot);
            }
            ex[p] = dot;
            unsigned u = __float_as_uint(dot);
            u ^= (unsigned)((int)u >> 31) | 0x80000000u;   // order-preserving transform
            us[p] = valid ? u : 0u;
        }

        // exact 64th-largest (fp32 domain) via 32-step bitwise ballot descent
        unsigned cut = 0u;
        #pragma unroll
        for (int b = 31; b >= 0; --b) {
            const unsigned trial = cut | (1u << b);
            const int cnt = __popcll(__ballot(us[0] >= trial)) +
                            __popcll(__ballot(us[1] >= trial));
            if (cnt >= TOPK) cut = trial;
        }

        // selection (ties on exact fp32 scores: lowest candidate position first)
        const unsigned long long beq0 = __ballot(us[0] == cut);
        const unsigned long long beq1 = __ballot(us[1] == cut);
        const int cntGt = __popcll(__ballot(us[0] > cut)) + __popcll(__ballot(us[1] > cut));
        const int need  = TOPK - cntGt;
        const int rank0 = __popcll(beq0 & mlt);
        const int rank1 = __popcll(beq0) + __popcll(beq1 & mlt);
        const bool sel0 = (us[0] > cut) || ((us[0] == cut) && (rank0 < need));
        const bool sel1 = (us[1] > cut) || ((us[1] == cut) && (rank1 < need));

        // softmax over selected (exact fp32)
        float mxe = fmaxf(sel0 ? ex[0] : -1e30f, sel1 ? ex[1] : -1e30f);
        #pragma unroll
        for (int o = 32; o > 0; o >>= 1) mxe = fmaxf(mxe, __shfl_xor(mxe, o));
        const float w0 = sel0 ? expf(ex[0] - mxe) : 0.f;
        const float w1 = sel1 ? expf(ex[1] - mxe) : 0.f;
        float zs = w0 + w1;
        #pragma unroll
        for (int o = 32; o > 0; o >>= 1) zs += __shfl_xor(zs, o);
        const float inv = 1.f / zs;

        // compact selected (key, weight) pairs
        pvK[wave][lane] = 0;          // defensive init (poisoned LDS)
        pvW[wave][lane] = 0.f;
        const unsigned long long bs0 = __ballot(sel0);
        const unsigned long long bs1 = __ballot(sel1);
        const int pos0 = __popcll(bs0 & mlt);
        const int pos1 = __popcll(bs0) + __popcll(bs1 & mlt);
        if (sel0) { pvK[wave][pos0] = ci[0]; pvW[wave][pos0] = w0 * inv; }
        if (sel1) { pvK[wave][pos1] = ci[1]; pvW[wave][pos1] = w1 * inv; }
        asm volatile("s_waitcnt lgkmcnt(0)" ::: "memory");

        // PV: lane = d, gather 64 V rows (coalesced 256B per row)
        float acc = 0.f;
        #pragma unroll 16
        for (int i = 0; i < TOPK; ++i) {
            const int   ki = pvK[wave][i];
            const float wi = pvW[wave][i];
            acc = fmaf(wi, Vf[(headbase + ki) * DIM + lane], acc);
        }
        Out[(rowbase + row) * DIM + lane] = acc;
    }
}

extern "C" void kernel_launch(void* const* d_in, const int* in_sizes, int n_in,
                              void* d_out, int out_size, void* d_ws, size_t ws_size,
                              hipStream_t stream)
{
    const float* Q = (const float*)d_in[0];
    const float* K = (const float*)d_in[1];
    const float* V = (const float*)d_in[2];
    float* Out = (float*)d_out;

    const int nElem = 2 * 16 * 2048 * 64;   // 4194304 per tensor
    const size_t needWs = (size_t)2 * (size_t)nElem * sizeof(_Float16);

    if (ws_size >= needWs) {
        _Float16* Q16 = (_Float16*)d_ws;
        _Float16* K16 = Q16 + nElem;
        cvt_f16_kernel<<<(nElem / 4) / 256, 256, 0, stream>>>(Q, K, Q16, K16, nElem / 4);
        topk_attn_kernel<true><<<NROWTOT / ROWS, 512, 0, stream>>>(Q, K, V, Q16, K16, Out);
    } else {
        topk_attn_kernel<false><<<NROWTOT / ROWS, 512, 0, stream>>>(Q, K, V, nullptr, nullptr, Out);
    }
}